// Round 1
// baseline (9761.201 us; speedup 1.0000x reference)
//
#include <hip/hip_runtime.h>

// Problem constants (B=128, T=256, H=1024, V=4096)
#define T_STEPS 256
#define BATCH   128
#define HDIM    1024
#define VDIM    4096
#define BH      (BATCH * HDIM)

typedef _Float16 half8 __attribute__((ext_vector_type(8)));
typedef _Float16 half4 __attribute__((ext_vector_type(4)));
typedef float    floatx4 __attribute__((ext_vector_type(4)));

__device__ __forceinline__ half8 ld_h8(const _Float16* p) { return *(const half8*)p; }

__device__ __forceinline__ void async16(void* l, const void* g) {
  // global->LDS DMA, 16B per lane; LDS dest = wave-uniform base + lane*16
  __builtin_amdgcn_global_load_lds(
      (const __attribute__((address_space(1))) unsigned int*)g,
      (__attribute__((address_space(3))) unsigned int*)l, 16, 0, 0);
}

// ---------------- grid barrier (generation / sense-reversing) ----------------
// bar[0] = arrive counter, bar[1] = generation. Both zeroed per launch.
__device__ __forceinline__ void grid_barrier(unsigned* bar, unsigned nwg) {
  __syncthreads();  // drains vmcnt: all wg stores complete before arrive
  if (threadIdx.x == 0) {
    unsigned g = __hip_atomic_load(&bar[1], __ATOMIC_RELAXED, __HIP_MEMORY_SCOPE_AGENT);
    unsigned a = __hip_atomic_fetch_add(&bar[0], 1u, __ATOMIC_ACQ_REL, __HIP_MEMORY_SCOPE_AGENT);
    if (a == nwg - 1u) {
      __hip_atomic_store(&bar[0], 0u, __ATOMIC_RELAXED, __HIP_MEMORY_SCOPE_AGENT);
      __hip_atomic_store(&bar[1], g + 1u, __ATOMIC_RELEASE, __HIP_MEMORY_SCOPE_AGENT);
    } else {
      while (__hip_atomic_load(&bar[1], __ATOMIC_RELAXED, __HIP_MEMORY_SCOPE_AGENT) == g) {
        __builtin_amdgcn_s_sleep(2);
      }
      // single acquire to invalidate caches once after the spin
      (void)__hip_atomic_load(&bar[1], __ATOMIC_ACQUIRE, __HIP_MEMORY_SCOPE_AGENT);
    }
  }
  __syncthreads();
}

// ---------------- fp32 -> fp16 weight conversion ----------------
__global__ __launch_bounds__(256) void f32_to_f16_kernel(
    const float* __restrict__ in, _Float16* __restrict__ out, int n4) {
  int i = blockIdx.x * 256 + threadIdx.x;
  if (i < n4) {
    float4 v = ((const float4*)in)[i];
    half4 h;
    h[0] = (_Float16)v.x; h[1] = (_Float16)v.y;
    h[2] = (_Float16)v.z; h[3] = (_Float16)v.w;
    ((half4*)out)[i] = h;
  }
}

// ---------------- persistent recurrent kernel ----------------
// Grid: 256 wgs x 256 thr (1/CU). wgs [0,128): layer0, [128,256): layer1.
// Pipelined: phase p computes h0(p) and h1(p-1); one grid barrier per phase.
// Per wg: [16 rows x 64 cols] tile; per wave: 16 cols, 2 independent K-chains.
__global__ __launch_bounds__(256) void rnn_kernel(
    const float* __restrict__ x,      // [B, T] (x[b,0,t])
    const float* __restrict__ Wih0,   // [H]
    const float* __restrict__ bih0, const float* __restrict__ bhh0,
    const float* __restrict__ bih1, const float* __restrict__ bhh1,
    const _Float16* __restrict__ W0h, // [H][H] fp16 (row j, k contiguous)
    const _Float16* __restrict__ W1i, // [H][H]
    const _Float16* __restrict__ W1h, // [H][H]
    _Float16* __restrict__ h0buf,     // [2][B][H] fp16 (buf 1 zeroed)
    _Float16* __restrict__ h1h,       // [T+1][B][H] fp16 (slot 0 zeroed); slot s = h1(s-1)
    float* __restrict__ outh,         // d_out + B*T*V : [2][B][H] fp32
    unsigned* __restrict__ bar) {
  const int tid  = threadIdx.x;
  const int wv   = tid >> 6;
  const int lane = tid & 63;
  const int l15  = lane & 15;
  const int q    = lane >> 4;

  const int bid   = blockIdx.x;
  const int layer = bid >> 7;
  const int sub   = bid & 127;
  const int rowg  = sub & 7;        // 8 row-groups of 16 rows
  const int colg  = sub >> 3;       // 16 col-groups of 64 cols
  const int rowbase = rowg * 16;
  const int colbase = colg * 64 + wv * 16;
  const int j = colbase + l15;      // output column this lane owns (B-frag row)
  const int aoff = q * 8;           // k-block within a 32-wide MFMA step

  for (int p = 0; p <= T_STEPS; ++p) {
    if (layer == 0) {
      if (p < T_STEPS) {
        // h0(p) = tanh(x_p * Wih0 + W_hh0 . h0(p-1) + b0)
        const _Float16* A = h0buf + ((p + 1) & 1) * BH;
        _Float16*       D = h0buf + (p & 1) * BH;
        const _Float16* ar = A   + (rowbase + l15) * HDIM + aoff;
        const _Float16* br = W0h + j * HDIM + aoff;
        floatx4 acc0 = {0.f, 0.f, 0.f, 0.f}, acc1 = {0.f, 0.f, 0.f, 0.f};
#pragma unroll
        for (int k = 0; k < 512; k += 32) {
          acc0 = __builtin_amdgcn_mfma_f32_16x16x32_f16(ld_h8(ar + k),       ld_h8(br + k),       acc0, 0, 0, 0);
          acc1 = __builtin_amdgcn_mfma_f32_16x16x32_f16(ld_h8(ar + 512 + k), ld_h8(br + 512 + k), acc1, 0, 0, 0);
        }
        floatx4 z = acc0 + acc1;
        float w0 = Wih0[j];
        float bb = bih0[j] + bhh0[j];
#pragma unroll
        for (int r = 0; r < 4; ++r) {
          int b = rowbase + q * 4 + r;           // D row = q*4+reg
          float h = tanhf(z[r] + x[b * T_STEPS + p] * w0 + bb);
          D[b * HDIM + j] = (_Float16)h;
          if (p == T_STEPS - 1) outh[b * HDIM + j] = h;
        }
      }
    } else {
      if (p >= 1) {
        // h1(i) = tanh(W_ih1 . h0(i) + W_hh1 . h1(i-1) + b1), i = p-1
        const int i = p - 1;
        const _Float16* A1 = h0buf + (i & 1) * BH;   // h0(i)
        const _Float16* A2 = h1h + i * BH;           // h1(i-1)
        _Float16*       D  = h1h + (i + 1) * BH;
        const _Float16* a1 = A1  + (rowbase + l15) * HDIM + aoff;
        const _Float16* a2 = A2  + (rowbase + l15) * HDIM + aoff;
        const _Float16* b1 = W1i + j * HDIM + aoff;
        const _Float16* b2 = W1h + j * HDIM + aoff;
        floatx4 acc0 = {0.f, 0.f, 0.f, 0.f}, acc1 = {0.f, 0.f, 0.f, 0.f};
#pragma unroll
        for (int k = 0; k < 512; k += 32) {
          acc0 = __builtin_amdgcn_mfma_f32_16x16x32_f16(ld_h8(a1 + k),       ld_h8(b1 + k),       acc0, 0, 0, 0);
          acc1 = __builtin_amdgcn_mfma_f32_16x16x32_f16(ld_h8(a1 + 512 + k), ld_h8(b1 + 512 + k), acc1, 0, 0, 0);
        }
#pragma unroll
        for (int k = 0; k < 512; k += 32) {
          acc0 = __builtin_amdgcn_mfma_f32_16x16x32_f16(ld_h8(a2 + k),       ld_h8(b2 + k),       acc0, 0, 0, 0);
          acc1 = __builtin_amdgcn_mfma_f32_16x16x32_f16(ld_h8(a2 + 512 + k), ld_h8(b2 + 512 + k), acc1, 0, 0, 0);
        }
        floatx4 z = acc0 + acc1;
        float bb = bih1[j] + bhh1[j];
#pragma unroll
        for (int r = 0; r < 4; ++r) {
          int b = rowbase + q * 4 + r;
          float h = tanhf(z[r] + bb);
          D[b * HDIM + j] = (_Float16)h;
          if (i == T_STEPS - 1) outh[BH + b * HDIM + j] = h;
        }
      }
    }
    if (p < T_STEPS) grid_barrier(bar, 256u);
  }
}

// ---------------- FC GEMM: out[b,t,v] = h1(t) . W_fc[v,:] + b_fc[v] ----------------
// A = h1 history [T*B][H] fp16, B = W_fc [V][H] fp16 (B^T form). 128x128 tile/wg.
__global__ __launch_bounds__(256) void fc_kernel(
    const _Float16* __restrict__ A,    // h1h + BH
    const _Float16* __restrict__ Wfc,  // [V][H] fp16
    const float* __restrict__ bfc,     // [V]
    float* __restrict__ out) {         // [B][T][V]
  __shared__ __align__(16) _Float16 As[128 * 64];
  __shared__ __align__(16) _Float16 Bs[128 * 64];
  const int tid  = threadIdx.x;
  const int wv   = tid >> 6;
  const int lane = tid & 63;
  const int l15  = lane & 15;
  const int q    = lane >> 4;
  const int t    = blockIdx.y;   // M-tile == one timestep (128 b rows)
  const int vt   = blockIdx.x;   // N-tile

  const _Float16* Ag = A   + (size_t)t * BH;
  const _Float16* Bg = Wfc + (size_t)vt * 128 * HDIM;

  floatx4 acc[4][4];
#pragma unroll
  for (int i = 0; i < 4; ++i)
#pragma unroll
    for (int jj = 0; jj < 4; ++jj) { floatx4 zz = {0.f,0.f,0.f,0.f}; acc[i][jj] = zz; }

  const int rowoff = (wv >> 1) * 64;
  const int coloff = (wv & 1) * 64;
  const int wbase  = wv * 1024;   // wave-uniform LDS byte offset

  for (int kk = 0; kk < HDIM; kk += 64) {
    // stage A,B tiles [128 x 64] fp16 with XOR(row&7) chunk swizzle
#pragma unroll
    for (int r = 0; r < 4; ++r) {
      int c   = r * 256 + tid;         // chunk 0..1023; LDS byte off = c*16
      int row = c >> 3;
      int gch = ((c & 7) ^ (row & 7)) << 3;  // swizzled source chunk (halves)
      async16((char*)As + r * 4096 + wbase, Ag + row * HDIM + kk + gch);
      async16((char*)Bs + r * 4096 + wbase, Bg + row * HDIM + kk + gch);
    }
    __syncthreads();
#pragma unroll
    for (int k2 = 0; k2 < 64; k2 += 32) {
      half8 af[4], bf[4];
      const int w = (k2 >> 3) + q;     // wanted chunk index 0..7
#pragma unroll
      for (int i = 0; i < 4; ++i) {
        int rA = rowoff + i * 16 + l15;
        af[i] = *(const half8*)&As[rA * 64 + ((w ^ (rA & 7)) << 3)];
        int rB = coloff + i * 16 + l15;
        bf[i] = *(const half8*)&Bs[rB * 64 + ((w ^ (rB & 7)) << 3)];
      }
#pragma unroll
      for (int i = 0; i < 4; ++i)
#pragma unroll
        for (int jj = 0; jj < 4; ++jj)
          acc[i][jj] = __builtin_amdgcn_mfma_f32_16x16x32_f16(af[i], bf[jj], acc[i][jj], 0, 0, 0);
    }
    __syncthreads();
  }

#pragma unroll
  for (int i = 0; i < 4; ++i) {
    int b0 = rowoff + i * 16 + q * 4;
#pragma unroll
    for (int jj = 0; jj < 4; ++jj) {
      int v = vt * 128 + coloff + jj * 16 + l15;
      float bias = bfc[v];
#pragma unroll
      for (int r = 0; r < 4; ++r) {
        long o = (long)(b0 + r) * (T_STEPS * VDIM) + (long)t * VDIM + v;
        out[o] = acc[i][jj][r] + bias;
      }
    }
  }
}

// ---------------- launch ----------------
extern "C" void kernel_launch(void* const* d_in, const int* in_sizes, int n_in,
                              void* d_out, int out_size, void* d_ws, size_t ws_size,
                              hipStream_t stream) {
  const float* x    = (const float*)d_in[0];
  const float* Wih0 = (const float*)d_in[1];
  const float* Whh0 = (const float*)d_in[2];
  const float* bih0 = (const float*)d_in[3];
  const float* bhh0 = (const float*)d_in[4];
  const float* Wih1 = (const float*)d_in[5];
  const float* Whh1 = (const float*)d_in[6];
  const float* bih1 = (const float*)d_in[7];
  const float* bhh1 = (const float*)d_in[8];
  const float* Wfc  = (const float*)d_in[9];
  const float* bfc  = (const float*)d_in[10];

  // workspace layout (~82.6 MB total)
  char* w = (char*)d_ws;
  unsigned* bar   = (unsigned*)w;                         // 256 B
  _Float16* h0buf = (_Float16*)(w + 256);                 // 2*BH fp16 = 512 KB
  _Float16* h1h   = (_Float16*)(w + 256 + 2 * BH * 2);    // (T+1)*BH fp16
  size_t off = 256 + (size_t)2 * BH * 2 + (size_t)(T_STEPS + 1) * BH * 2;
  _Float16* W0h16 = (_Float16*)(w + off); off += (size_t)HDIM * HDIM * 2;
  _Float16* W1i16 = (_Float16*)(w + off); off += (size_t)HDIM * HDIM * 2;
  _Float16* W1h16 = (_Float16*)(w + off); off += (size_t)HDIM * HDIM * 2;
  _Float16* Wfc16 = (_Float16*)(w + off); off += (size_t)VDIM * HDIM * 2;

  // zero: barrier state, h0buf[1] (=h0(-1)), h1h slot 0 (=h1(-1)) (contiguous)
  hipMemsetAsync(bar, 0, 256, stream);
  hipMemsetAsync((void*)(h0buf + BH), 0, (size_t)2 * BH * 2, stream);

  // weight conversion fp32 -> fp16
  f32_to_f16_kernel<<<(HDIM * HDIM / 4 + 255) / 256, 256, 0, stream>>>(Whh0, W0h16, HDIM * HDIM / 4);
  f32_to_f16_kernel<<<(HDIM * HDIM / 4 + 255) / 256, 256, 0, stream>>>(Wih1, W1i16, HDIM * HDIM / 4);
  f32_to_f16_kernel<<<(HDIM * HDIM / 4 + 255) / 256, 256, 0, stream>>>(Whh1, W1h16, HDIM * HDIM / 4);
  f32_to_f16_kernel<<<(VDIM * HDIM / 4 + 255) / 256, 256, 0, stream>>>(Wfc, Wfc16, VDIM * HDIM / 4);

  float* outh = (float*)d_out + (size_t)BATCH * T_STEPS * VDIM;
  rnn_kernel<<<256, 256, 0, stream>>>(x, Wih0, bih0, bhh0, bih1, bhh1,
                                      W0h16, W1i16, W1h16, h0buf, h1h, outh, bar);

  fc_kernel<<<dim3(32, 256), 256, 0, stream>>>(h1h + BH, Wfc16, bfc, (float*)d_out);
}